// Round 11
// baseline (417.246 us; speedup 1.0000x reference)
//
#include <hip/hip_runtime.h>
#include <math.h>

#define NB 8192
#define BATCH 2
#define KNN 20
#define BN (BATCH*NB)
#define NE (BN*KNN)
#define BIG 3.0e38f

#define GS 32
#define GS3 (GS*GS*GS)
#define CELL 0.3125f
#define GMIN -5.0f
#define INVC 3.2f
#define MARGIN 1.0e-2f
#define FIXG 128

__device__ __forceinline__ float gelu_f(float x){
    float x3 = x*x*x;
    float a = 0.7978845608028654f*(x + 0.044715f*x3);
    float e2 = __expf(2.0f*a);
    float th = 1.0f - __fdividef(2.0f, e2+1.0f);
    return 0.5f*x*(1.0f+th);
}

// ascending bitonic sort of v across 64 lanes (proven network from R4-R10)
__device__ __forceinline__ float bitonic_val(float v, int lane){
    #pragma unroll
    for (int K=2; K<=64; K<<=1){
        #pragma unroll
        for (int j=K>>1; j>0; j>>=1){
            float o = __shfl_xor(v, j);
            bool keepmin = (((lane & j) == 0) == ((lane & K) == 0));
            float mn = fminf(v,o), mx = fmaxf(v,o);
            v = keepmin ? mn : mx;
        }
    }
    return v;
}

// ---------------- K1: prep + cellid + zero hist/sus + cond MLP (blocks 0,1) ----------------
__global__ __launch_bounds__(256) void prepcond_kernel(const float* __restrict__ z,
        const float* __restrict__ t,
        const float* __restrict__ conditioning,
        const float* __restrict__ Wc1, const float* __restrict__ bc1,
        const float* __restrict__ Wc2, const float* __restrict__ bc2,
        const float* __restrict__ Wc3, const float* __restrict__ bc3,
        const float* __restrict__ We1, const float* __restrict__ be1,
        const float* __restrict__ We2,
        const float* __restrict__ Wn1, const float* __restrict__ bn1,
        float4* __restrict__ pos4, float4* __restrict__ vel4,
        int* __restrict__ cellid, int* __restrict__ histg,
        int* __restrict__ sus_cnt,
        float* __restrict__ consts, float* __restrict__ pack){
    int tid = threadIdx.x;
    int g = blockIdx.x*256 + tid;
    const float* zp = z + (size_t)g*7;
    float x = zp[0], y = zp[1], zz = zp[2];
    float r2 = x*x + y*y + zz*zz;
    pos4[g] = make_float4(x, y, zz, r2);
    vel4[g] = make_float4(zp[3], zp[4], zp[5], zp[6]);
    int cx = (int)floorf((x  - GMIN)*INVC); cx = min(GS-1, max(0, cx));
    int cy = (int)floorf((y  - GMIN)*INVC); cy = min(GS-1, max(0, cy));
    int cz = (int)floorf((zz - GMIN)*INVC); cz = min(GS-1, max(0, cz));
    cellid[g] = (cx*GS + cy)*GS + cz;
    histg[g] = 0; histg[g+16384] = 0; histg[g+32768] = 0; histg[g+49152] = 0;
    if (g == 0) sus_cnt[0] = 0;

    if (blockIdx.x >= BATCH) return;
    int b = blockIdx.x;
    __shared__ float ci[36];
    __shared__ float h1[144];
    __shared__ float h2[144];
    __shared__ float cnd[36];
    float tv = t[b];
    if (tid < 16){
        float f = expf(-9.210340371976184f * (float)tid / 15.0f);
        float a = tv*f;
        ci[tid]    = sinf(a);
        ci[16+tid] = cosf(a);
    }
    if (tid < 4) ci[32+tid] = conditioning[b*4+tid];
    __syncthreads();
    if (tid < 144){
        float acc = bc1[tid];
        #pragma unroll
        for (int c=0;c<36;c++) acc += ci[c]*Wc1[c*144+tid];
        h1[tid] = gelu_f(acc);
    }
    __syncthreads();
    if (tid < 144){
        float acc = bc2[tid];
        #pragma unroll 36
        for (int c=0;c<144;c++) acc += h1[c]*Wc2[c*144+tid];
        h2[tid] = gelu_f(acc);
    }
    __syncthreads();
    if (tid < 36){
        float acc = bc3[tid];
        #pragma unroll 36
        for (int c=0;c<144;c++) acc += h2[c]*Wc3[c*36+tid];
        cnd[tid] = acc;
    }
    __syncthreads();
    if (tid < 128){
        float accC = be1[tid], s1 = 0.f, s2 = 0.f;
        #pragma unroll
        for (int c=0;c<36;c++){
            float w1 = We1[c*128+tid];
            float w2 = We1[(36+c)*128+tid];
            accC += cnd[c]*(w1+w2);
            s1 += w1; s2 += w2;
        }
        consts[b*128+tid] = accC;
        pack[b*1536 + tid*12 + 0] = accC;
        if (b==0){
            consts[256+tid] = s1; consts[384+tid] = s2;
            float vals[10];
            vals[0] = s1; vals[1] = s2;
            vals[2] = We1[72*128+tid];
            vals[3] = We1[73*128+tid];
            vals[4] = We1[74*128+tid];
            vals[5] = We1[75*128+tid];
            vals[6] = We2[tid*4+0];
            vals[7] = We2[tid*4+1];
            vals[8] = We2[tid*4+2];
            vals[9] = We2[tid*4+3];
            #pragma unroll
            for (int q=0;q<10;q++){
                pack[tid*12 + 1 + q]        = vals[q];
                pack[1536 + tid*12 + 1 + q] = vals[q];
            }
        }
    }
    if (tid < 64){
        float accD = bn1[tid], t1 = 0.f;
        #pragma unroll
        for (int c=0;c<36;c++){
            float w = Wn1[c*64+tid];
            accD += cnd[c]*w;
            t1 += w;
        }
        consts[512 + b*64 + tid] = accD;
        if (b==0) consts[640+tid] = t1;
    }
}

// ---------------- K2: cell histogram (global atomics; hist zeroed in K1) ----------------
__global__ __launch_bounds__(256) void hist_kernel(const int* __restrict__ cellid,
                                                   int* __restrict__ histg){
    int g = blockIdx.x*256 + threadIdx.x;
    atomicAdd(&histg[(g>>13)*GS3 + cellid[g]], 1);
}

// ---------------- K3: per-batch scan + scatter into cell-sorted order ----------------
__global__ __launch_bounds__(1024) void gridsort_kernel(const int* __restrict__ cellid,
        const float4* __restrict__ pos4,
        int* __restrict__ histg, int* __restrict__ cellStart,
        float4* __restrict__ sortedPos4, int* __restrict__ sortedIdx){
    int b = blockIdx.x;
    int tid = threadIdx.x;
    int* H = histg + b*GS3;
    int* CSg = cellStart + b*(GS3+1);
    __shared__ int tsum[1024];

    int base_c = tid*32;
    int s = 0;
    #pragma unroll 8
    for (int j=0;j<32;j++) s += H[base_c+j];
    tsum[tid] = s;
    __syncthreads();
    // Hillis-Steele inclusive scan
    for (int o=1;o<1024;o<<=1){
        int v = (tid>=o) ? tsum[tid-o] : 0;
        __syncthreads();
        tsum[tid] += v;
        __syncthreads();
    }
    int run = tsum[tid] - s;   // exclusive prefix
    #pragma unroll 8
    for (int j=0;j<32;j++){
        int c = base_c + j;
        int cc = H[c];
        CSg[c] = run;
        H[c] = run;            // becomes running pointer for scatter
        run += cc;
    }
    if (tid == 0) CSg[GS3] = NB;
    __threadfence();
    __syncthreads();
    #pragma unroll
    for (int q=0;q<8;q++){
        int g = b*NB + q*1024 + tid;
        int c = cellid[g];
        int p = atomicAdd(&H[c], 1);
        sortedPos4[b*NB + p] = pos4[g];
        sortedIdx[b*NB + p]  = g & (NB-1);
    }
}

// ---------------- K4: exact grid KNN, wave per node (sorted order for locality) ----------------
__global__ __launch_bounds__(256) void knn_grid(const float4* __restrict__ SPall,
        const int* __restrict__ SIall,
        const int* __restrict__ CSall,
        int* __restrict__ nbr,
        int* __restrict__ sus_cnt, int* __restrict__ sus_id){
    __shared__ float2 sC[4*64];
    int tid = threadIdx.x;
    int w = tid >> 6, lane = tid & 63;
    int p = blockIdx.x*4 + w;            // sorted slot
    int b = p >> 13;
    int pl = p & (NB-1);
    const float4* __restrict__ SP = SPall + b*NB;
    const int*   __restrict__ SI = SIall + b*NB;
    const int*   __restrict__ CS = CSall + b*(GS3+1);
    float4 pi = SP[pl];
    int i = SI[pl];                      // original local index
    float pwv = pi.w;
    float nx = -2.0f*pi.x, ny = -2.0f*pi.y, nz = -2.0f*pi.z;
    int cx = (int)floorf((pi.x - GMIN)*INVC); cx = min(GS-1, max(0, cx));
    int cy = (int)floorf((pi.y - GMIN)*INVC); cy = min(GS-1, max(0, cy));
    int cz = (int)floorf((pi.z - GMIN)*INVC); cz = min(GS-1, max(0, cz));

    float T = BIG;
    int xlo, xhi, ylo, yhi, zlo, zhi;
    for (int R = 1;; ++R){
        xlo = max(cx-R,0); xhi = min(cx+R,GS-1);
        ylo = max(cy-R,0); yhi = min(cy+R,GS-1);
        zlo = max(cz-R,0); zhi = min(cz+R,GS-1);
        bool full = (xlo==0) && (xhi==GS-1) && (ylo==0) && (yhi==GS-1)
                 && (zlo==0) && (zhi==GS-1);
        float accd = BIG;
        int fill = 0;
        for (int X=xlo; X<=xhi; ++X)
            for (int Y=ylo; Y<=yhi; ++Y){
                int basec = (X*GS + Y)*GS;
                int s = CS[basec+zlo];
                int e = CS[basec+zhi+1];
                for (int c=s; c<e; c+=64){
                    int len = e - c; if (len > 64) len = 64;
                    int slot = (lane - fill) & 63;      // cyclic fill -> >=20 lanes hold candidates
                    if (slot < len){
                        float4 q = SP[c+slot];
                        float d2 = fmaf(nx,q.x, fmaf(ny,q.y, fmaf(nz,q.z, pwv+q.w)));
                        if (SI[c+slot] == i) d2 = BIG;  // exclude self
                        accd = fminf(accd, d2);
                    }
                    fill += len;
                }
            }
        if (full || fill >= 21){
            float v = bitonic_val(accd, lane);
            T = __shfl(v, 19);          // 20th smallest lane-min >= d20 (exact bound)
            if (full) break;
            float bnd = BIG;
            if (xlo > 0)    bnd = fminf(bnd, pi.x - (GMIN + xlo*CELL));
            if (xhi < GS-1) bnd = fminf(bnd, (GMIN + (xhi+1)*CELL) - pi.x);
            if (ylo > 0)    bnd = fminf(bnd, pi.y - (GMIN + ylo*CELL));
            if (yhi < GS-1) bnd = fminf(bnd, (GMIN + (yhi+1)*CELL) - pi.y);
            if (zlo > 0)    bnd = fminf(bnd, pi.z - (GMIN + zlo*CELL));
            if (zhi < GS-1) bnd = fminf(bnd, (GMIN + (zhi+1)*CELL) - pi.z);
            // outside points have true d2 >= bnd^2; formula error << MARGIN
            if (bnd > 0.0f && fmaf(bnd, bnd, -MARGIN) > T) break;
        }
    }

    // ---- pass B: collect all candidates <= T in final region ----
    int cnt = 0;
    unsigned long long lt = (1ull << lane) - 1ull;
    for (int X=xlo; X<=xhi; ++X)
        for (int Y=ylo; Y<=yhi; ++Y){
            int basec = (X*GS + Y)*GS;
            int s = CS[basec+zlo];
            int e = CS[basec+zhi+1];
            for (int c=s; c<e; c+=64){
                int len = e - c; if (len > 64) len = 64;
                bool hit = false; float d2 = BIG; int id = 0;
                if (lane < len){
                    float4 q = SP[c+lane];
                    id = SI[c+lane];
                    d2 = fmaf(nx,q.x, fmaf(ny,q.y, fmaf(nz,q.z, pwv+q.w)));
                    hit = (d2 <= T) && (id != i);
                }
                unsigned long long m = __ballot(hit);
                if (m){
                    if (hit){
                        int off = cnt + (int)__popcll(m & lt);
                        if (off < 64) sC[w*64 + off] = make_float2(d2, __int_as_float(id));
                    }
                    cnt += (int)__popcll(m);
                }
            }
        }
    if (cnt > 64 && lane == 0){         // overflow: exact fixup handles this node
        int sl = atomicAdd(sus_cnt, 1);
        sus_id[sl] = b*NB + i;
    }
    int mm = cnt > 64 ? 64 : cnt;
    float d; int idx;
    if (lane < mm){
        float2 e2 = sC[w*64 + lane];
        d = e2.x; idx = __float_as_int(e2.y);
    } else { d = BIG; idx = 0x7f000000 + lane; }
    #pragma unroll
    for (int K=2; K<=64; K<<=1){
        #pragma unroll
        for (int j=K>>1; j>0; j>>=1){
            float od = __shfl_xor(d, j);
            int   oi = __shfl_xor(idx, j);
            bool pless = (od < d) || (od == d && oi < idx);
            bool keepmin = (((lane & j) == 0) == ((lane & K) == 0));
            if (pless == keepmin){ d = od; idx = oi; }
        }
    }
    if (lane < KNN) nbr[(size_t)(b*NB + i)*KNN + lane] = idx;
}

// ---------------- K5: fixup — exact top-8/lane + pop-merge full scan (R5/R6-proven) ----------------
__global__ __launch_bounds__(64) void fixup_kernel(const float4* __restrict__ pos4,
                                                   const int* __restrict__ sus_cnt,
                                                   const int* __restrict__ sus_id,
                                                   int* __restrict__ nbr){
    int lane = threadIdx.x;
    int nsus = sus_cnt[0];
    for (int s = blockIdx.x; s < nsus; s += FIXG){
        int node = sus_id[s];
        int b = node >> 13;
        int i = node & (NB-1);
        const float4* __restrict__ P = pos4 + b*NB;
        float4 pi = P[i];
        float pwv = pi.w;
        float n2x = -2.0f*pi.x, n2y = -2.0f*pi.y, n2z = -2.0f*pi.z;

        float bd[8]; int bi8[8];
        #pragma unroll
        for (int r=0;r<8;r++){ bd[r] = BIG; bi8[r] = 0x7fffffff; }
        for (int tk=0; tk<128; ++tk){
            int j = (tk<<6) + lane;
            float4 q = P[j];
            float d2 = fmaf(n2x,q.x, fmaf(n2y,q.y, fmaf(n2z,q.z, pwv+q.w)));
            if (j == i) d2 = BIG;
            if (d2 < bd[7]){
                float vd = d2; int vi = j;
                #pragma unroll
                for (int r=0;r<8;r++){
                    bool c = vd < bd[r];
                    float td = bd[r]; int ti = bi8[r];
                    bd[r] = c ? vd : td;  bi8[r] = c ? vi : ti;
                    vd    = c ? td : vd;  vi    = c ? ti : vi;
                }
            }
        }
        int* outp = nbr + (size_t)node*KNN;
        for (int r=0; r<KNN; r++){
            float d = bd[0]; int ii = bi8[0];
            #pragma unroll
            for (int st=1; st<64; st<<=1){
                float od = __shfl_xor(d, st);
                int   oi = __shfl_xor(ii, st);
                if (od < d || (od == d && oi < ii)){ d = od; ii = oi; }
            }
            if (lane == 0) outp[r] = ii;
            if (bd[0] == d && bi8[0] == ii){
                #pragma unroll
                for (int st=0;st<7;st++){ bd[st]=bd[st+1]; bi8[st]=bi8[st+1]; }
                bd[7] = BIG; bi8[7] = 0x7fffffff;
            }
        }
    }
}

// ---------------- K6: fused edge MLP (2 edges/thread, s_load weights) + softmax + node MLP ----------------
__global__ __launch_bounds__(320) void edgenode_kernel(const float4* __restrict__ pos4,
        const float4* __restrict__ vel4,
        const int* __restrict__ nbr,
        const float* __restrict__ pack,
        const float* __restrict__ consts,
        const float* __restrict__ Wn1,
        const float* __restrict__ Wn2,
        const float* __restrict__ be2,
        const float* __restrict__ bn2,
        const float* __restrict__ alpha_p,
        const float* __restrict__ beta_p,
        const float* __restrict__ z,
        float* __restrict__ out){
    __shared__ float sLg[640], sSm[640], sUx[640], sUy[640], sUz[640];
    __shared__ float sD[64], sT1[64], sW36[64], sWo[64];
    __shared__ float4 sAgg[32];
    __shared__ float sPart[256];

    int tid = threadIdx.x;
    bool bb = (blockIdx.x >= 256);
    const float* __restrict__ pk = pack + (bb ? 1536 : 0);

    if (tid < 64){
        sD[tid]   = consts[512 + (bb?64:0) + tid];
        sT1[tid]  = consts[640+tid];
        sW36[tid] = Wn1[36*64+tid];
        sWo[tid]  = Wn2[tid];
    }

    int base_e = blockIdx.x*640;
    int bbase = bb ? NB : 0;

    float rx[2],ry[2],rz[2],vsx[2],vsy[2],vsz[2];
    float r2[2],vv[2],vsr[2],vtr[2],mfs[2],mft[2];
    #pragma unroll
    for (int r=0;r<2;r++){
        int le = tid + 320*r;
        int i = blockIdx.x*32 + le/KNN;
        int s = nbr[base_e + le];
        float4 ps = pos4[bbase + s], pt = pos4[i];
        float4 vs = vel4[bbase + s], vt = vel4[i];
        rx[r] = ps.x - pt.x; ry[r] = ps.y - pt.y; rz[r] = ps.z - pt.z;
        vsx[r] = vs.x; vsy[r] = vs.y; vsz[r] = vs.z;
        r2[r]  = rx[r]*rx[r] + ry[r]*ry[r] + rz[r]*rz[r];
        vv[r]  = vs.x*vt.x + vs.y*vt.y + vs.z*vt.z;
        vsr[r] = vs.x*rx[r] + vs.y*ry[r] + vs.z*rz[r];
        vtr[r] = vt.x*rx[r] + vt.y*ry[r] + vt.z*rz[r];
        mfs[r] = vs.w; mft[r] = vt.w;
    }

    float b2v0 = be2[0], b2v1 = be2[1], b2v2 = be2[2], b2v3 = be2[3];
    float a0[2], a1[2], a2[2], a3[2];
    #pragma unroll
    for (int r=0;r<2;r++){ a0[r]=b2v0; a1[r]=b2v1; a2[r]=b2v2; a3[r]=b2v3; }
    #pragma unroll 4
    for (int h=0; h<128; h++){
        const float4* row = (const float4*)(pk + h*12);
        float4 A  = row[0];
        float4 Bv = row[1];
        float4 C  = row[2];
        #pragma unroll
        for (int r=0;r<2;r++){
            float x = fmaf(mfs[r],A.y, A.x) + mft[r]*A.z
                    + r2[r]*A.w + vv[r]*Bv.x + vsr[r]*Bv.y + vtr[r]*Bv.z;
            float gx = gelu_f(x);
            a0[r] += gx*Bv.w; a1[r] += gx*C.x; a2[r] += gx*C.y; a3[r] += gx*C.z;
        }
    }
    #pragma unroll
    for (int r=0;r<2;r++){
        int le = tid + 320*r;
        sLg[le] = a0[r];
        sSm[le] = a1[r];
        sUx[le] = a2[r]*rx[r] + a3[r]*vsx[r];
        sUy[le] = a2[r]*ry[r] + a3[r]*vsy[r];
        sUz[le] = a2[r]*rz[r] + a3[r]*vsz[r];
    }
    __syncthreads();

    if (tid < 32){
        int base = tid*KNN;
        float m = -BIG;
        #pragma unroll
        for (int q=0;q<KNN;q++) m = fmaxf(m, sLg[base+q]);
        float den=0.f, wx=0.f, wy=0.f, wz=0.f, wsm=0.f;
        #pragma unroll
        for (int q=0;q<KNN;q++){
            float a = __expf(sLg[base+q]-m);
            den += a;
            wsm += a*sSm[base+q];
            wx  += a*sUx[base+q];
            wy  += a*sUy[base+q];
            wz  += a*sUz[base+q];
        }
        float inv = __fdividef(1.0f, den);
        sAgg[tid] = make_float4(wx*inv, wy*inv, wz*inv, wsm*inv);
    }
    __syncthreads();

    if (tid < 256){
        int ln = tid >> 3;
        int h0 = (tid & 7)*8;
        float mf = vel4[blockIdx.x*32 + ln].w;
        float sg = sAgg[ln].w;
        float part = 0.f;
        #pragma unroll
        for (int h=h0; h<h0+8; h++){
            float x = sD[h] + mf*sT1[h] + sg*sW36[h];
            part += gelu_f(x)*sWo[h];
        }
        sPart[tid] = part;
    }
    __syncthreads();

    if (tid < 32){
        float sout = bn2[0];
        #pragma unroll
        for (int q=0;q<8;q++) sout += sPart[tid*8+q];
        int node = blockIdx.x*32 + tid;
        float alpha = alpha_p[0], beta = beta_p[0];
        float4 ag = sAgg[tid];
        const float* zp = z + (size_t)node*7;
        float* op = out + (size_t)node*7;
        op[0] = zp[0]*2.0f + alpha*ag.x;
        op[1] = zp[1]*2.0f + alpha*ag.y;
        op[2] = zp[2]*2.0f + alpha*ag.z;
        op[3] = zp[3] + beta*ag.x;
        op[4] = zp[4] + beta*ag.y;
        op[5] = zp[5] + beta*ag.z;
        op[6] = zp[6] + sout;
    }
}

extern "C" void kernel_launch(void* const* d_in, const int* in_sizes, int n_in,
                              void* d_out, int out_size, void* d_ws, size_t ws_size,
                              hipStream_t stream) {
    const float* z    = (const float*)d_in[0];
    const float* t    = (const float*)d_in[1];
    const float* cond = (const float*)d_in[2];
    const float* Wc1  = (const float*)d_in[4];
    const float* bc1  = (const float*)d_in[5];
    const float* Wc2  = (const float*)d_in[6];
    const float* bc2  = (const float*)d_in[7];
    const float* Wc3  = (const float*)d_in[8];
    const float* bc3  = (const float*)d_in[9];
    const float* We1  = (const float*)d_in[10];
    const float* be1  = (const float*)d_in[11];
    const float* We2  = (const float*)d_in[12];
    const float* be2  = (const float*)d_in[13];
    const float* Wn1  = (const float*)d_in[14];
    const float* bn1  = (const float*)d_in[15];
    const float* Wn2  = (const float*)d_in[16];
    const float* bn2  = (const float*)d_in[17];
    const float* alp  = (const float*)d_in[18];
    const float* bet  = (const float*)d_in[19];
    float* out = (float*)d_out;

    char* ws = (char*)d_ws;
    float4* pos4    = (float4*)(ws);                     // 262144
    float4* vel4    = (float4*)(ws + 262144);            // 262144
    float*  consts  = (float*)(ws + 524288);             // 4096
    float*  pack    = (float*)(ws + 528384);             // 12288
    int*    nbr     = (int*)(ws + 540672);               // 1310720
    int*    cellid  = (int*)(ws + 1851392);              // 65536
    int*    histg   = (int*)(ws + 1916928);              // 262144
    int*    cellSt  = (int*)(ws + 2179072);              // 262160
    float4* sPos4   = (float4*)(ws + 2441232);           // 262144
    int*    sIdx    = (int*)(ws + 2703376);              // 65536
    int*    sus_c   = (int*)(ws + 2768912);              // 256
    int*    sus_id  = (int*)(ws + 2769168);              // 65536

    prepcond_kernel<<<dim3(BN/256), dim3(256), 0, stream>>>(z, t, cond,
        Wc1, bc1, Wc2, bc2, Wc3, bc3, We1, be1, We2, Wn1, bn1,
        pos4, vel4, cellid, histg, sus_c, consts, pack);
    hist_kernel<<<dim3(BN/256), dim3(256), 0, stream>>>(cellid, histg);
    gridsort_kernel<<<dim3(BATCH), dim3(1024), 0, stream>>>(cellid, pos4, histg, cellSt,
                                                            sPos4, sIdx);
    knn_grid<<<dim3(BN/4), dim3(256), 0, stream>>>(sPos4, sIdx, cellSt, nbr, sus_c, sus_id);
    fixup_kernel<<<dim3(FIXG), dim3(64), 0, stream>>>(pos4, sus_c, sus_id, nbr);
    edgenode_kernel<<<dim3(BN/32), dim3(320), 0, stream>>>(pos4, vel4, nbr, pack, consts,
        Wn1, Wn2, be2, bn2, alp, bet, z, out);
}

// Round 12
// 207.718 us; speedup vs baseline: 2.0087x; 2.0087x over previous
//
#include <hip/hip_runtime.h>
#include <math.h>

#define NB 8192
#define BATCH 2
#define KNN 20
#define BN (BATCH*NB)
#define NE (BN*KNN)        // 327680 edges
#define GT 16              // tiles per staged group (16 KB)
#define NG 8               // groups per pass
#define BIG 3.0e38f

__device__ __forceinline__ float gelu_f(float x){
    float x3 = x*x*x;
    float a = 0.7978845608028654f*(x + 0.044715f*x3);
    float e2 = __expf(2.0f*a);
    float th = 1.0f - __fdividef(2.0f, e2+1.0f);
    return 0.5f*x*(1.0f+th);
}

// ---------------- K1: prep (all 64 blocks) + cond MLP (blocks 0,1) ----------------
// consts floats: C[2][128]@0, S1[128]@256, S2[128]@384, D[2][64]@512, T1[64]@640
// pack per h (128): {C0,C1,S1,S2, W72,W73,W74,W75, V0,V1,V2,V3} = 12 floats
__global__ __launch_bounds__(256) void prepcond_kernel(const float* __restrict__ z,
        const float* __restrict__ t,
        const float* __restrict__ conditioning,
        const float* __restrict__ Wc1, const float* __restrict__ bc1,
        const float* __restrict__ Wc2, const float* __restrict__ bc2,
        const float* __restrict__ Wc3, const float* __restrict__ bc3,
        const float* __restrict__ We1, const float* __restrict__ be1,
        const float* __restrict__ We2,
        const float* __restrict__ Wn1, const float* __restrict__ bn1,
        float4* __restrict__ pos4, float4* __restrict__ vel4,
        float* __restrict__ consts, float* __restrict__ pack){
    int tid = threadIdx.x;
    int g = blockIdx.x*256 + tid;
    const float* zp = z + (size_t)g*7;
    float x = zp[0], y = zp[1], zz = zp[2];
    float r2 = x*x + y*y + zz*zz;
    pos4[g] = make_float4(x, y, zz, r2);
    vel4[g] = make_float4(zp[3], zp[4], zp[5], zp[6]);

    if (blockIdx.x >= BATCH) return;
    int b = blockIdx.x;
    __shared__ float ci[36];
    __shared__ float h1[144];
    __shared__ float h2[144];
    __shared__ float cnd[36];
    float tv = t[b];
    if (tid < 16){
        float f = expf(-9.210340371976184f * (float)tid / 15.0f);
        float a = tv*f;
        ci[tid]    = sinf(a);
        ci[16+tid] = cosf(a);
    }
    if (tid < 4) ci[32+tid] = conditioning[b*4+tid];
    __syncthreads();
    if (tid < 144){
        float acc = bc1[tid];
        #pragma unroll
        for (int c=0;c<36;c++) acc += ci[c]*Wc1[c*144+tid];
        h1[tid] = gelu_f(acc);
    }
    __syncthreads();
    if (tid < 144){
        float acc = bc2[tid];
        #pragma unroll 36
        for (int c=0;c<144;c++) acc += h1[c]*Wc2[c*144+tid];
        h2[tid] = gelu_f(acc);
    }
    __syncthreads();
    if (tid < 36){
        float acc = bc3[tid];
        #pragma unroll 36
        for (int c=0;c<144;c++) acc += h2[c]*Wc3[c*36+tid];
        cnd[tid] = acc;
    }
    __syncthreads();
    if (tid < 128){
        float accC = be1[tid], s1 = 0.f, s2 = 0.f;
        #pragma unroll
        for (int c=0;c<36;c++){
            float w1 = We1[c*128+tid];
            float w2 = We1[(36+c)*128+tid];
            accC += cnd[c]*(w1+w2);
            s1 += w1; s2 += w2;
        }
        consts[b*128+tid] = accC;
        pack[tid*12 + b] = accC;
        if (b==0){
            consts[256+tid] = s1; consts[384+tid] = s2;
            pack[tid*12+2] = s1;
            pack[tid*12+3] = s2;
            pack[tid*12+4] = We1[72*128+tid];
            pack[tid*12+5] = We1[73*128+tid];
            pack[tid*12+6] = We1[74*128+tid];
            pack[tid*12+7] = We1[75*128+tid];
            pack[tid*12+8]  = We2[tid*4+0];
            pack[tid*12+9]  = We2[tid*4+1];
            pack[tid*12+10] = We2[tid*4+2];
            pack[tid*12+11] = We2[tid*4+3];
        }
    }
    if (tid < 64){
        float accD = bn1[tid], t1 = 0.f;
        #pragma unroll
        for (int c=0;c<36;c++){
            float w = Wn1[c*64+tid];
            accD += cnd[c]*w;
            t1 += w;
        }
        consts[512 + b*64 + tid] = accD;
        if (b==0) consts[640+tid] = t1;
    }
}

// ---------------- K2: fused KNN + select (proven two-pass), 8 waves x 4 nodes ----------------
// Pass A: per-lane min -> bitonic-64 -> T = 20th smallest (exact upper bound on d20)
// Pass B: rescan from LDS, ballot-compact d2<=T into LDS cand, bitonic by (d2,idx), top-20
__global__ __launch_bounds__(512, 4) void knn_kernel(const float4* __restrict__ pos4,
                                                     int* __restrict__ nbr){
    __shared__ float4 sPos[GT*64];      // 16 KB
    __shared__ float2 sCand[32*64];     // 16 KB
    int tid = threadIdx.x;
    int w = tid >> 6, lane = tid & 63;
    int n0g = blockIdx.x * 32;
    int b = n0g >> 13;
    int n0 = n0g & (NB-1);
    const float4* __restrict__ P = pos4 + b*NB;

    int nw = n0 + w*4;
    float nx[4], ny[4], nz[4], pw[4], acc[4];
    #pragma unroll
    for (int k=0;k<4;k++){
        float4 p = P[nw+k];
        nx[k] = -2.0f*p.x; ny[k] = -2.0f*p.y; nz[k] = -2.0f*p.z; pw[k] = p.w;
        acc[k] = BIG;
    }
    int selfTile = n0 >> 6;            // all 32 block nodes share one tile
    int sl0 = (n0 & 63) + w*4;         // self lane for node k is sl0+k

    // ---- Pass A ----
    float4 pre0 = P[(w*2    )*64 + lane];
    float4 pre1 = P[(w*2 + 1)*64 + lane];
    for (int g=0; g<NG; ++g){
        __syncthreads();
        sPos[(w*2    )*64 + lane] = pre0;
        sPos[(w*2 + 1)*64 + lane] = pre1;
        if (g+1 < NG){
            pre0 = P[((g+1)*GT + w*2    )*64 + lane];
            pre1 = P[((g+1)*GT + w*2 + 1)*64 + lane];
        }
        __syncthreads();
        int tbase = g*GT;
        #pragma unroll
        for (int t=0;t<GT;t++){
            float4 q = sPos[t*64 + lane];
            if (tbase + t != selfTile){
                #pragma unroll
                for (int k=0;k<4;k++){
                    float d2 = fmaf(nx[k],q.x, fmaf(ny[k],q.y, fmaf(nz[k],q.z, pw[k]+q.w)));
                    acc[k] = fminf(acc[k], d2);
                }
            } else {
                #pragma unroll
                for (int k=0;k<4;k++){
                    float d2 = fmaf(nx[k],q.x, fmaf(ny[k],q.y, fmaf(nz[k],q.z, pw[k]+q.w)));
                    if (lane == sl0 + k) d2 = BIG;
                    acc[k] = fminf(acc[k], d2);
                }
            }
        }
    }

    // ---- T[k] = 20th smallest of 64 per-lane minima ----
    float T[4];
    #pragma unroll
    for (int k=0;k<4;k++){
        float v = acc[k];
        #pragma unroll
        for (int K=2; K<=64; K<<=1){
            #pragma unroll
            for (int j=K>>1; j>0; j>>=1){
                float o = __shfl_xor(v, j);
                bool keepmin = (((lane & j) == 0) == ((lane & K) == 0));
                float mn = fminf(v,o), mx = fmaxf(v,o);
                v = keepmin ? mn : mx;
            }
        }
        T[k] = __shfl(v, 19);
    }

    // ---- Pass B: collect into LDS ----
    int cnt[4];
    #pragma unroll
    for (int k=0;k<4;k++) cnt[k] = 0;
    unsigned long long lt = (1ull << lane) - 1ull;

    pre0 = P[(w*2    )*64 + lane];
    pre1 = P[(w*2 + 1)*64 + lane];
    for (int g=0; g<NG; ++g){
        __syncthreads();
        sPos[(w*2    )*64 + lane] = pre0;
        sPos[(w*2 + 1)*64 + lane] = pre1;
        if (g+1 < NG){
            pre0 = P[((g+1)*GT + w*2    )*64 + lane];
            pre1 = P[((g+1)*GT + w*2 + 1)*64 + lane];
        }
        __syncthreads();
        int tbase = g*GT;
        #pragma unroll 4
        for (int t=0;t<GT;t++){
            int tile = tbase + t;
            float4 q = sPos[t*64 + lane];
            int j = (tile<<6) + lane;
            bool selft = (tile == selfTile);
            #pragma unroll
            for (int k=0;k<4;k++){
                float d2 = fmaf(nx[k],q.x, fmaf(ny[k],q.y, fmaf(nz[k],q.z, pw[k]+q.w)));
                bool hit = (d2 <= T[k]);
                if (selft && (lane == sl0 + k)) hit = false;
                unsigned long long m = __ballot(hit);
                if (m){
                    if (hit){
                        int off = cnt[k] + (int)__popcll(m & lt);
                        if (off < 64)
                            sCand[(w*4+k)*64 + off] = make_float2(d2, __int_as_float(j));
                    }
                    cnt[k] += (int)__popcll(m);
                }
            }
        }
    }

    // ---- sort each node's candidates (same-wave data; no barrier needed) ----
    #pragma unroll
    for (int k=0;k<4;k++){
        int m = cnt[k]; if (m > 64) m = 64;
        float d; int idx;
        if (lane < m){
            float2 e = sCand[(w*4+k)*64 + lane];
            d = e.x; idx = __float_as_int(e.y);
        } else { d = BIG; idx = 0x7f000000 + lane; }
        #pragma unroll
        for (int K=2; K<=64; K<<=1){
            #pragma unroll
            for (int j=K>>1; j>0; j>>=1){
                float od = __shfl_xor(d, j);
                int   oi = __shfl_xor(idx, j);
                bool pless = (od < d) || (od == d && oi < idx);
                bool keepmin = (((lane & j) == 0) == ((lane & K) == 0));
                if (pless == keepmin){ d = od; idx = oi; }
            }
        }
        if (lane < KNN) nbr[(size_t)(n0g + w*4 + k)*KNN + lane] = idx;
    }
}

// ---------------- K3: fused edge MLP + softmax-aggregate + node MLP + output ----------------
// 1024 blocks x 320 threads; block owns 16 nodes = 320 edges exactly.
__global__ __launch_bounds__(320) void edgenode_kernel(const float4* __restrict__ pos4,
        const float4* __restrict__ vel4,
        const int* __restrict__ nbr,
        const float* __restrict__ pack,
        const float* __restrict__ consts,
        const float* __restrict__ Wn1,
        const float* __restrict__ Wn2,
        const float* __restrict__ be2,
        const float* __restrict__ bn2,
        const float* __restrict__ alpha_p,
        const float* __restrict__ beta_p,
        const float* __restrict__ z,
        float* __restrict__ out){
    __shared__ float4 sP[384];                       // 6 KB edge weights
    __shared__ float sLg[320], sSm[320], sUx[320], sUy[320], sUz[320];  // 6.25 KB
    __shared__ float sD[64], sT1[64], sW36[64], sWo[64];
    __shared__ float sMf[16];
    __shared__ float4 sAgg[16];                      // {vax,vay,vaz,sagg}
    __shared__ float sPart[320];

    int tid = threadIdx.x;
    bool bb = (blockIdx.x >= 512);                   // batch block-uniform
    for (int k=tid; k<384; k+=320) sP[k] = ((const float4*)pack)[k];
    if (tid < 64){
        sD[tid]   = consts[512 + (bb?64:0) + tid];
        sT1[tid]  = consts[640+tid];
        sW36[tid] = Wn1[36*64+tid];
        sWo[tid]  = Wn2[tid];
    }

    int e = blockIdx.x*320 + tid;
    int i = e / KNN;                   // global tgt node
    int ln = tid / KNN;                // local node 0..15
    int r  = tid - ln*KNN;             // edge rank 0..19
    int bbase = bb ? NB : 0;
    int s = nbr[e];
    float4 ps = pos4[bbase + s], pt = pos4[i];
    float4 vs = vel4[bbase + s], vt = vel4[i];
    if (r == 0) sMf[ln] = vt.w;

    float rx = ps.x - pt.x, ry = ps.y - pt.y, rz = ps.z - pt.z;
    float r2  = rx*rx + ry*ry + rz*rz;
    float vv  = vs.x*vt.x + vs.y*vt.y + vs.z*vt.z;
    float vsr = vs.x*rx + vs.y*ry + vs.z*rz;
    float vtr = vt.x*rx + vt.y*ry + vt.z*rz;
    float mfs = vs.w, mft = vt.w;
    __syncthreads();   // sP ready

    float a0 = be2[0], a1 = be2[1], a2 = be2[2], a3 = be2[3];
    #pragma unroll 4
    for (int h=0; h<128; h++){
        float4 A  = sP[h*3];
        float4 Bv = sP[h*3+1];
        float4 C  = sP[h*3+2];
        float base = bb ? A.y : A.x;
        float x = base + mfs*A.z + mft*A.w + r2*Bv.x + vv*Bv.y + vsr*Bv.z + vtr*Bv.w;
        float gx = gelu_f(x);
        a0 += gx*C.x; a1 += gx*C.y; a2 += gx*C.z; a3 += gx*C.w;
    }
    sLg[tid] = a0;
    sSm[tid] = a1;
    sUx[tid] = a2*rx + a3*vs.x;
    sUy[tid] = a2*ry + a3*vs.y;
    sUz[tid] = a2*rz + a3*vs.z;
    __syncthreads();

    // per-node softmax + aggregation (16 serial lanes)
    if (tid < 16){
        int base = tid*KNN;
        float m = -BIG;
        #pragma unroll
        for (int q=0;q<KNN;q++) m = fmaxf(m, sLg[base+q]);
        float den=0.f, wx=0.f, wy=0.f, wz=0.f, wsm=0.f;
        #pragma unroll
        for (int q=0;q<KNN;q++){
            float a = __expf(sLg[base+q]-m);
            den += a;
            wsm += a*sSm[base+q];
            wx  += a*sUx[base+q];
            wy  += a*sUy[base+q];
            wz  += a*sUz[base+q];
        }
        float inv = __fdividef(1.0f, den);
        sAgg[tid] = make_float4(wx*inv, wy*inv, wz*inv, wsm*inv);
    }
    __syncthreads();

    // node MLP partials: 20 threads per node, h = r, r+20, r+40, (r+60)
    {
        float mf = sMf[ln];
        float sg = sAgg[ln].w;
        float part = 0.f;
        #pragma unroll
        for (int h=r; h<64; h+=KNN){
            float x = sD[h] + mf*sT1[h] + sg*sW36[h];
            part += gelu_f(x)*sWo[h];
        }
        sPart[tid] = part;
    }
    __syncthreads();

    if (tid < 16){
        float sout = bn2[0];
        #pragma unroll
        for (int q=0;q<KNN;q++) sout += sPart[tid*KNN+q];
        int node = blockIdx.x*16 + tid;
        float alpha = alpha_p[0], beta = beta_p[0];
        float4 ag = sAgg[tid];
        const float* zp = z + (size_t)node*7;
        float* op = out + (size_t)node*7;
        op[0] = zp[0]*2.0f + alpha*ag.x;
        op[1] = zp[1]*2.0f + alpha*ag.y;
        op[2] = zp[2]*2.0f + alpha*ag.z;
        op[3] = zp[3] + beta*ag.x;
        op[4] = zp[4] + beta*ag.y;
        op[5] = zp[5] + beta*ag.z;
        op[6] = zp[6] + sout;
    }
}

extern "C" void kernel_launch(void* const* d_in, const int* in_sizes, int n_in,
                              void* d_out, int out_size, void* d_ws, size_t ws_size,
                              hipStream_t stream) {
    const float* z    = (const float*)d_in[0];
    const float* t    = (const float*)d_in[1];
    const float* cond = (const float*)d_in[2];
    const float* Wc1  = (const float*)d_in[4];
    const float* bc1  = (const float*)d_in[5];
    const float* Wc2  = (const float*)d_in[6];
    const float* bc2  = (const float*)d_in[7];
    const float* Wc3  = (const float*)d_in[8];
    const float* bc3  = (const float*)d_in[9];
    const float* We1  = (const float*)d_in[10];
    const float* be1  = (const float*)d_in[11];
    const float* We2  = (const float*)d_in[12];
    const float* be2  = (const float*)d_in[13];
    const float* Wn1  = (const float*)d_in[14];
    const float* bn1  = (const float*)d_in[15];
    const float* Wn2  = (const float*)d_in[16];
    const float* bn2  = (const float*)d_in[17];
    const float* alp  = (const float*)d_in[18];
    const float* bet  = (const float*)d_in[19];
    float* out = (float*)d_out;

    char* ws = (char*)d_ws;
    float4* pos4   = (float4*)(ws);                      // 262144 B
    float4* vel4   = (float4*)(ws + 262144);             // 262144 B
    float*  consts = (float*)(ws + 524288);              // 4096 B
    float*  pack   = (float*)(ws + 528384);              // 6144 B
    int*    nbr    = (int*)(ws + 534528);                // 1310720 B

    prepcond_kernel<<<dim3(BN/256), dim3(256), 0, stream>>>(z, t, cond,
        Wc1, bc1, Wc2, bc2, Wc3, bc3, We1, be1, We2, Wn1, bn1,
        pos4, vel4, consts, pack);
    knn_kernel<<<dim3(BN/32), dim3(512), 0, stream>>>(pos4, nbr);
    edgenode_kernel<<<dim3(BN/16), dim3(320), 0, stream>>>(pos4, vel4, nbr, pack, consts,
        Wn1, Wn2, be2, bn2, alp, bet, z, out);
}